// Round 12
// baseline (396.251 us; speedup 1.0000x reference)
//
#include <hip/hip_runtime.h>
#include <hip/hip_bf16.h>
#include <math.h>

// Problem constants
#define HW_N   16384
#define DIM    256
#define NSEL   4096
#define NQ     1024
#define NHEAD  8
#define HD     32
#define NP_    25
#define DFF_   1024
#define NQOUT  632    // fused query-GEMM output width (200 aw | 32 ob | 400 dgrid)

// Workspace layout (float offsets). ~80 MB total.
#define OFF_SELREF  8448LL          // 2*4096*7
#define OFF_SELSRC  65792LL         // 2*4096*256
#define OFF_SELPOS  2162944LL       // 2*4096*256 (later reused as boxout bf16)
#define OFF_QUERY   4260096LL       // 2*4096*256 (query bf16, later src2 fp32)
#define OFF_BIG     6357248LL       // vproj bf16 [0,4194304) then ffnt bf16 same slot
#define OFF_WBF     10551552LL      // OFF_BIG+4194304: bf16 weights, 1079296 bf16
#define OFF_QBIAS   11151552LL      // packed query bias, 632 floats (inside WBF region slack)
#define OFF_F       14745856LL      // multi-use region, 5177344 floats

__device__ __forceinline__ unsigned int f2s(float f) {
    unsigned int u = __float_as_uint(f);
    return (u & 0x80000000u) ? ~u : (u | 0x80000000u);
}

typedef __bf16 bf16x8 __attribute__((ext_vector_type(8)));
typedef __bf16 bf16x4 __attribute__((ext_vector_type(4)));
typedef float  f32x4  __attribute__((ext_vector_type(4)));

// ============ weight preconversion: 9 fp32 matrices -> one bf16 pool ============
extern "C" __global__ __launch_bounds__(256)
void wcvt_kernel(const float* __restrict__ s0, const float* __restrict__ s1,
                 const float* __restrict__ s2, const float* __restrict__ s3,
                 const float* __restrict__ s4, const float* __restrict__ s5,
                 const float* __restrict__ s6, const float* __restrict__ s7,
                 const float* __restrict__ s8, __hip_bfloat16* __restrict__ dst) {
    const long long g = (long long)blockIdx.x * 256 + threadIdx.x;
    const float* s; long long base;
    if      (g < 196608)  { s = s0; base = 0; }
    else if (g < 262144)  { s = s1; base = 196608; }
    else if (g < 327680)  { s = s2; base = 262144; }
    else if (g < 378880)  { s = s3; base = 327680; }
    else if (g < 387072)  { s = s4; base = 378880; }
    else if (g < 489472)  { s = s5; base = 387072; }
    else if (g < 555008)  { s = s6; base = 489472; }
    else if (g < 817152)  { s = s7; base = 555008; }
    else                  { s = s8; base = 817152; }
    dst[g] = __float2bfloat16(s[g - base]);
}

// ============ pack query biases: [lin_attn_b | lin_box_b | samp_off_b] ============
extern "C" __global__ __launch_bounds__(256)
void qbias_kernel(const float* __restrict__ a, const float* __restrict__ b,
                  const float* __restrict__ c, float* __restrict__ d) {
    const int t = blockIdx.x * 256 + threadIdx.x;
    if (t < 200)      d[t] = a[t];
    else if (t < 232) d[t] = b[t - 200];
    else if (t < 632) d[t] = c[t - 232];
}

// ================= top-k, grid-parallel (4 kernels) =================
extern "C" __global__ __launch_bounds__(512)
void topk_hist_kernel(const float* __restrict__ score, unsigned int* __restrict__ hist) {
    const int t = threadIdx.x, bx = blockIdx.x, bb = blockIdx.y;
    const int i = bx * 512 + t;
    unsigned int u = f2s(score[(long long)bb * HW_N + i]);
    atomicAdd(&hist[bb * 8192 + (u >> 19)], 1u);
}

extern "C" __global__ __launch_bounds__(1024)
void topk_scan_kernel(const unsigned int* __restrict__ hist, unsigned int* __restrict__ ctrl) {
    __shared__ unsigned int scan[1024];
    const int t = threadIdx.x, bb = blockIdx.x;
    unsigned int loc[8]; unsigned int lsum = 0u;
    #pragma unroll
    for (int k = 0; k < 8; ++k) { loc[k] = hist[bb * 8192 + t * 8 + k]; lsum += loc[k]; }
    scan[t] = lsum;
    __syncthreads();
    for (int off = 1; off < 1024; off <<= 1) {
        unsigned int v = (t + off < 1024) ? scan[t + off] : 0u;
        __syncthreads();
        scan[t] += v;
        __syncthreads();
    }
    unsigned int nxt = (t < 1023) ? scan[t + 1] : 0u;
    unsigned int run = nxt;
    for (int k = 7; k >= 0; --k) {
        run += loc[k];
        unsigned int above = run - loc[k];
        if (run >= 1024u && above < 1024u) { ctrl[bb * 16 + 0] = (unsigned)(t * 8 + k); ctrl[bb * 16 + 1] = 1024u - above; }
        if (run >= 4096u && above < 4096u) { ctrl[bb * 16 + 2] = (unsigned)(t * 8 + k); ctrl[bb * 16 + 3] = 4096u - above; }
    }
}

extern "C" __global__ __launch_bounds__(1024)
void topk_collect_kernel(const float* __restrict__ score, unsigned int* __restrict__ ctrl,
                         unsigned long long* __restrict__ list1,
                         unsigned long long* __restrict__ list2) {
    const int t = threadIdx.x, bx = blockIdx.x, bb = blockIdx.y;
    const int i = bx * 1024 + t;
    const unsigned int T1 = ctrl[bb * 16 + 0], T2 = ctrl[bb * 16 + 2];
    unsigned int u = f2s(score[(long long)bb * HW_N + i]);
    unsigned int bin = u >> 19;
    unsigned long long key = ((unsigned long long)u << 32) | (unsigned int)(~(unsigned int)i);
    if (bin == T1) {
        unsigned int p = atomicAdd(&ctrl[bb * 16 + 4], 1u);
        if (p < 2048u) list1[bb * 2048 + p] = key;
    }
    if (bin == T2 && T2 != T1) {
        unsigned int p = atomicAdd(&ctrl[bb * 16 + 5], 1u);
        if (p < 2048u) list2[bb * 2048 + p] = key;
    }
}

extern "C" __global__ __launch_bounds__(1024)
void topk_classify_kernel(const float* __restrict__ score, unsigned int* __restrict__ ctrl,
                          const unsigned long long* __restrict__ list1,
                          const unsigned long long* __restrict__ list2,
                          int* __restrict__ idx_out) {
    __shared__ unsigned int cA, cB, baseA, baseB;
    const int t = threadIdx.x, bx = blockIdx.x, bb = blockIdx.y;
    const int i = bx * 1024 + t;
    if (t == 0) { cA = 0u; cB = 0u; }
    __syncthreads();
    const unsigned int T1 = ctrl[bb * 16 + 0], need1 = ctrl[bb * 16 + 1];
    const unsigned int T2 = ctrl[bb * 16 + 2], need2 = ctrl[bb * 16 + 3];
    const unsigned int c1 = min(ctrl[bb * 16 + 4], 2048u);
    const unsigned int c2 = min(ctrl[bb * 16 + 5], 2048u);
    unsigned int u = f2s(score[(long long)bb * HW_N + i]);
    unsigned int bin = u >> 19;
    unsigned long long key = ((unsigned long long)u << 32) | (unsigned int)(~(unsigned int)i);
    bool inA = false, inB = false;
    if (bin > T1) {
        inA = true;
    } else if (bin == T1) {
        unsigned int r = 0;
        for (unsigned int q = 0; q < c1; ++q) r += (list1[bb * 2048 + q] > key) ? 1u : 0u;
        if (r < need1) inA = true;
        else if (T2 == T1) inB = (r < need2);
        else inB = true;
    } else if (bin > T2) {
        inB = true;
    } else if (bin == T2) {
        unsigned int r = 0;
        for (unsigned int q = 0; q < c2; ++q) r += (list2[bb * 2048 + q] > key) ? 1u : 0u;
        inB = (r < need2);
    }
    unsigned int sA = 0u, sB = 0u;
    if (inA) sA = atomicAdd(&cA, 1u);
    if (inB) sB = atomicAdd(&cB, 1u);
    __syncthreads();
    if (t == 0) {
        baseA = atomicAdd(&ctrl[bb * 16 + 6], cA);
        baseB = atomicAdd(&ctrl[bb * 16 + 7], cB);
    }
    __syncthreads();
    if (inA) idx_out[bb * NSEL + baseA + sA] = i;
    if (inB) idx_out[bb * NSEL + 1024 + baseB + sB] = i;
}

// ---------------- gather selected rows (+ bf16 copies for MFMA A-operands) ----
extern "C" __global__ __launch_bounds__(256)
void gather_kernel(const float* __restrict__ src, const float* __restrict__ pos,
                   const float* __restrict__ refw, const int* __restrict__ idx,
                   float* __restrict__ selsrc, float* __restrict__ selpos,
                   float* __restrict__ selref,
                   __hip_bfloat16* __restrict__ qkb16,
                   __hip_bfloat16* __restrict__ selsrcb,
                   __hip_bfloat16* __restrict__ queryb) {
    const int s = blockIdx.x, bb = blockIdx.y, t = threadIdx.x;
    const int i = idx[bb * NSEL + s];
    const long long so = ((long long)(bb * NSEL + s)) * DIM;
    const long long go = ((long long)(bb * HW_N + i)) * DIM;
    float sv = src[go + t], pv = pos[go + t];
    selsrc[so + t] = sv;
    selpos[so + t] = pv;
    if (s < NQ) {
        const long long qo = ((long long)(bb * NQ + s)) * DIM + t;
        qkb16[qo] = __float2bfloat16(sv + pv);
        selsrcb[qo] = __float2bfloat16(sv);
    } else {
        queryb[so + t] = __float2bfloat16(sv + pv);
    }
    if (t < 7)
        selref[(long long)(bb * NSEL + s) * 7 + t] = refw[(long long)(bb * HW_N + i) * 7 + t];
}

// ---------------- bf16 MFMA GEMM (64x64 tile): C = act(A @ W^T + bias) --------
extern "C" __global__ __launch_bounds__(256)
void gemm_kernel(const void* __restrict__ Avp, long long sA,
                 const __hip_bfloat16* __restrict__ W, const float* __restrict__ bias,
                 float* __restrict__ C, long long sC,
                 int M, int N, int K, int relu, int omode, int amode) {
    __shared__ __hip_bfloat16 As[64][72];
    __shared__ __hip_bfloat16 Ws[64][72];
    const int t = threadIdx.x;
    const int n0 = blockIdx.x * 64, m0 = blockIdx.y * 64;
    const long long zoff = (long long)blockIdx.z * sC;
    const int lane = t & 63, wv = t >> 6;
    const int mw = (wv >> 1) * 32, nw = (wv & 1) * 32;
    const int fr = lane & 15;
    const int fk = (lane >> 4) * 8;
    const int sr = t >> 2;
    const int sk = (t & 3) * 16;

    f32x4 acc[2][2];
    #pragma unroll
    for (int i = 0; i < 2; ++i)
        #pragma unroll
        for (int j = 0; j < 2; ++j) acc[i][j] = {0.f, 0.f, 0.f, 0.f};

    const bool wok = (n0 + sr) < N;
    for (int k0 = 0; k0 < K; k0 += 64) {
        uint4 wa = make_uint4(0u, 0u, 0u, 0u), wb = make_uint4(0u, 0u, 0u, 0u);
        if (wok) {
            const __hip_bfloat16* wp = W + (long long)(n0 + sr) * K + k0 + sk;
            wa = *(const uint4*)wp;
            wb = *(const uint4*)(wp + 8);
        }
        if (amode) {
            const __hip_bfloat16* ap = (const __hip_bfloat16*)Avp
                + (long long)blockIdx.z * sA + (long long)(m0 + sr) * K + k0 + sk;
            uint4 aa = *(const uint4*)ap;
            uint4 ab = *(const uint4*)(ap + 8);
            __syncthreads();
            *(uint4*)&As[sr][sk] = aa;
            *(uint4*)&As[sr][sk + 8] = ab;
            *(uint4*)&Ws[sr][sk] = wa;
            *(uint4*)&Ws[sr][sk + 8] = wb;
        } else {
            const float* ap = (const float*)Avp
                + (long long)blockIdx.z * sA + (long long)(m0 + sr) * K + k0 + sk;
            float av[16];
            #pragma unroll
            for (int q = 0; q < 4; ++q) {
                float4 v = *(const float4*)(ap + q * 4);
                av[q * 4 + 0] = v.x; av[q * 4 + 1] = v.y; av[q * 4 + 2] = v.z; av[q * 4 + 3] = v.w;
            }
            __syncthreads();
            #pragma unroll
            for (int q = 0; q < 16; ++q) As[sr][sk + q] = __float2bfloat16(av[q]);
            *(uint4*)&Ws[sr][sk] = wa;
            *(uint4*)&Ws[sr][sk + 8] = wb;
        }
        __syncthreads();
        #pragma unroll
        for (int kk = 0; kk < 64; kk += 32) {
            bf16x8 a0 = *(const bf16x8*)&As[mw + fr][kk + fk];
            bf16x8 a1 = *(const bf16x8*)&As[mw + 16 + fr][kk + fk];
            bf16x8 b0 = *(const bf16x8*)&Ws[nw + fr][kk + fk];
            bf16x8 b1 = *(const bf16x8*)&Ws[nw + 16 + fr][kk + fk];
            acc[0][0] = __builtin_amdgcn_mfma_f32_16x16x32_bf16(a0, b0, acc[0][0], 0, 0, 0);
            acc[0][1] = __builtin_amdgcn_mfma_f32_16x16x32_bf16(a0, b1, acc[0][1], 0, 0, 0);
            acc[1][0] = __builtin_amdgcn_mfma_f32_16x16x32_bf16(a1, b0, acc[1][0], 0, 0, 0);
            acc[1][1] = __builtin_amdgcn_mfma_f32_16x16x32_bf16(a1, b1, acc[1][1], 0, 0, 0);
        }
    }
    const int crow = (lane >> 4) * 4;
    #pragma unroll
    for (int mi = 0; mi < 2; ++mi) {
        #pragma unroll
        for (int ni = 0; ni < 2; ++ni) {
            const int col = n0 + nw + ni * 16 + fr;
            if (col < N) {
                const float bv = bias ? bias[col] : 0.f;
                #pragma unroll
                for (int r = 0; r < 4; ++r) {
                    const int row = m0 + mw + mi * 16 + crow + r;
                    float v = acc[mi][ni][r] + bv;
                    if (relu) v = fmaxf(v, 0.f);
                    if (omode == 0) {
                        C[zoff + (long long)row * N + col] = v;
                    } else if (omode == 1) {
                        ((__hip_bfloat16*)C)[zoff + (long long)row * N + col] = __float2bfloat16(v);
                    } else if (omode == 2) {
                        ((__hip_bfloat16*)C)[zoff + (long long)col * M + row] = __float2bfloat16(v);
                    } else {
                        ((__hip_bfloat16*)C)[zoff + ((long long)(col >> 5) * 16384 + row) * 32 + (col & 31)]
                            = __float2bfloat16(v);
                    }
                }
            }
        }
    }
}

// ---------------- bf16 MFMA GEMM (128x128 tile, register-staged) --------------
// Ladder step 2 structure (m93, 517 TF): 4 waves, each owns a 64x64 quadrant
// (4x4 frags), 32 MFMA per wave per K-step against the same 2 barriers the
// 64^2 kernel pays for 8. Register staging only (global_load_lds machinery
// failed twice, R8/R9). REQUIRES M%128==0, N%128==0, K%64==0 (no guards).
// Same K accumulation order as gemm_kernel -> bit-identical outputs.
// omode: 0 fp32 flat; 1 bf16 flat; 3 bf16 head-planar. amode: 0 fp32 A; 1 bf16 A.
extern "C" __global__ __launch_bounds__(256)
void gemm128r_kernel(const void* __restrict__ Avp, long long sA,
                     const __hip_bfloat16* __restrict__ W, const float* __restrict__ bias,
                     float* __restrict__ C, long long sC,
                     int M, int N, int K, int relu, int omode, int amode) {
    __shared__ __hip_bfloat16 As[128][72];
    __shared__ __hip_bfloat16 Ws[128][72];
    const int t = threadIdx.x;
    const int n0 = blockIdx.x * 128, m0 = blockIdx.y * 128;
    const long long zoff = (long long)blockIdx.z * sC;
    const int lane = t & 63, wv = t >> 6;
    const int mq = (wv >> 1) * 64, nq = (wv & 1) * 64;
    const int fr = lane & 15;
    const int fk = (lane >> 4) * 8;
    const int sr = t >> 1;            // 0..127: staging row
    const int sk = (t & 1) * 32;      // 0 / 32: staging col half

    f32x4 acc[4][4];
    #pragma unroll
    for (int i = 0; i < 4; ++i)
        #pragma unroll
        for (int j = 0; j < 4; ++j) acc[i][j] = {0.f, 0.f, 0.f, 0.f};

    for (int k0 = 0; k0 < K; k0 += 64) {
        const __hip_bfloat16* wp = W + (long long)(n0 + sr) * K + k0 + sk;
        uint4 w0 = *(const uint4*)wp;
        uint4 w1 = *(const uint4*)(wp + 8);
        uint4 w2 = *(const uint4*)(wp + 16);
        uint4 w3 = *(const uint4*)(wp + 24);
        if (amode) {
            const __hip_bfloat16* ap = (const __hip_bfloat16*)Avp
                + (long long)blockIdx.z * sA + (long long)(m0 + sr) * K + k0 + sk;
            uint4 a0 = *(const uint4*)ap;
            uint4 a1 = *(const uint4*)(ap + 8);
            uint4 a2 = *(const uint4*)(ap + 16);
            uint4 a3 = *(const uint4*)(ap + 24);
            __syncthreads();
            *(uint4*)&As[sr][sk]      = a0;
            *(uint4*)&As[sr][sk + 8]  = a1;
            *(uint4*)&As[sr][sk + 16] = a2;
            *(uint4*)&As[sr][sk + 24] = a3;
        } else {
            const float* ap = (const float*)Avp
                + (long long)blockIdx.z * sA + (long long)(m0 + sr) * K + k0 + sk;
            float av[32];
            #pragma unroll
            for (int q = 0; q < 8; ++q) {
                float4 v = *(const float4*)(ap + q * 4);
                av[q * 4 + 0] = v.x; av[q * 4 + 1] = v.y; av[q * 4 + 2] = v.z; av[q * 4 + 3] = v.w;
            }
            __syncthreads();
            #pragma unroll
            for (int q = 0; q < 32; ++q) As[sr][sk + q] = __float2bfloat16(av[q]);
        }
        *(uint4*)&Ws[sr][sk]      = w0;
        *(uint4*)&Ws[sr][sk + 8]  = w1;
        *(uint4*)&Ws[sr][sk + 16] = w2;
        *(uint4*)&Ws[sr][sk + 24] = w3;
        __syncthreads();
        #pragma unroll
        for (int kk = 0; kk < 64; kk += 32) {
            bf16x8 av4[4], bv4[4];
            #pragma unroll
            for (int mi = 0; mi < 4; ++mi)
                av4[mi] = *(const bf16x8*)&As[mq + mi * 16 + fr][kk + fk];
            #pragma unroll
            for (int ni = 0; ni < 4; ++ni)
                bv4[ni] = *(const bf16x8*)&Ws[nq + ni * 16 + fr][kk + fk];
            #pragma unroll
            for (int mi = 0; mi < 4; ++mi)
                #pragma unroll
                for (int ni = 0; ni < 4; ++ni)
                    acc[mi][ni] = __builtin_amdgcn_mfma_f32_16x16x32_bf16(av4[mi], bv4[ni], acc[mi][ni], 0, 0, 0);
        }
        __syncthreads();
    }
    const int crow = (lane >> 4) * 4;
    #pragma unroll
    for (int mi = 0; mi < 4; ++mi) {
        #pragma unroll
        for (int ni = 0; ni < 4; ++ni) {
            const int col = n0 + nq + ni * 16 + fr;
            const float bv = bias ? bias[col] : 0.f;
            #pragma unroll
            for (int r = 0; r < 4; ++r) {
                const int row = m0 + mq + mi * 16 + crow + r;
                float v = acc[mi][ni][r] + bv;
                if (relu) v = fmaxf(v, 0.f);
                if (omode == 0) {
                    C[zoff + (long long)row * N + col] = v;
                } else if (omode == 1) {
                    ((__hip_bfloat16*)C)[zoff + (long long)row * N + col] = __float2bfloat16(v);
                } else {
                    ((__hip_bfloat16*)C)[zoff + ((long long)(col >> 5) * 16384 + row) * 32 + (col & 31)]
                        = __float2bfloat16(v);
                }
            }
        }
    }
}

// ---------------- dual in_proj GEMM: qkv (N=512) + vT (N=256, transposed) -----
extern "C" __global__ __launch_bounds__(256)
void gemm_dual_kernel(const __hip_bfloat16* __restrict__ A1,
                      const __hip_bfloat16* __restrict__ A2,
                      const __hip_bfloat16* __restrict__ W,
                      const float* __restrict__ bias,
                      __hip_bfloat16* __restrict__ C1,
                      __hip_bfloat16* __restrict__ C2) {
    __shared__ __hip_bfloat16 As[64][72];
    __shared__ __hip_bfloat16 Ws[64][72];
    const int t = threadIdx.x;
    const bool p2 = (blockIdx.x >= 8);
    const int n0 = (p2 ? (blockIdx.x - 8) : blockIdx.x) * 64;
    const int m0 = blockIdx.y * 64;
    const int z = blockIdx.z;
    const __hip_bfloat16* A  = (p2 ? A2 : A1) + (long long)z * (NQ * DIM);
    const __hip_bfloat16* Wp = W + (p2 ? 512 * 256 : 0);
    const float* bp = bias + (p2 ? 512 : 0);
    const int lane = t & 63, wv = t >> 6;
    const int mw = (wv >> 1) * 32, nw = (wv & 1) * 32;
    const int fr = lane & 15;
    const int fk = (lane >> 4) * 8;
    const int sr = t >> 2;
    const int sk = (t & 3) * 16;

    f32x4 acc[2][2];
    #pragma unroll
    for (int i = 0; i < 2; ++i)
        #pragma unroll
        for (int j = 0; j < 2; ++j) acc[i][j] = {0.f, 0.f, 0.f, 0.f};

    for (int k0 = 0; k0 < 256; k0 += 64) {
        const __hip_bfloat16* wp = Wp + (long long)(n0 + sr) * 256 + k0 + sk;
        uint4 wa = *(const uint4*)wp;
        uint4 wb = *(const uint4*)(wp + 8);
        const __hip_bfloat16* ap = A + (long long)(m0 + sr) * 256 + k0 + sk;
        uint4 aa = *(const uint4*)ap;
        uint4 ab = *(const uint4*)(ap + 8);
        __syncthreads();
        *(uint4*)&As[sr][sk] = aa;
        *(uint4*)&As[sr][sk + 8] = ab;
        *(uint4*)&Ws[sr][sk] = wa;
        *(uint4*)&Ws[sr][sk + 8] = wb;
        __syncthreads();
        #pragma unroll
        for (int kk = 0; kk < 64; kk += 32) {
            bf16x8 a0 = *(const bf16x8*)&As[mw + fr][kk + fk];
            bf16x8 a1 = *(const bf16x8*)&As[mw + 16 + fr][kk + fk];
            bf16x8 b0 = *(const bf16x8*)&Ws[nw + fr][kk + fk];
            bf16x8 b1 = *(const bf16x8*)&Ws[nw + 16 + fr][kk + fk];
            acc[0][0] = __builtin_amdgcn_mfma_f32_16x16x32_bf16(a0, b0, acc[0][0], 0, 0, 0);
            acc[0][1] = __builtin_amdgcn_mfma_f32_16x16x32_bf16(a0, b1, acc[0][1], 0, 0, 0);
            acc[1][0] = __builtin_amdgcn_mfma_f32_16x16x32_bf16(a1, b0, acc[1][0], 0, 0, 0);
            acc[1][1] = __builtin_amdgcn_mfma_f32_16x16x32_bf16(a1, b1, acc[1][1], 0, 0, 0);
        }
    }
    const int crow = (lane >> 4) * 4;
    #pragma unroll
    for (int mi = 0; mi < 2; ++mi) {
        #pragma unroll
        for (int ni = 0; ni < 2; ++ni) {
            const int col = n0 + nw + ni * 16 + fr;
            const float bv = bp[col];
            #pragma unroll
            for (int r = 0; r < 4; ++r) {
                const int row = m0 + mw + mi * 16 + crow + r;
                float v = acc[mi][ni][r] + bv;
                if (!p2) {
                    C1[(long long)z * (NQ * 512) + (long long)row * 512 + col] = __float2bfloat16(v);
                } else {
                    C2[(long long)z * (NQ * 256) + (long long)col * NQ + row] = __float2bfloat16(v);
                }
            }
        }
    }
}

// ---------------- MHA via MFMA: 16 queries/block, S & softmax in registers ----
extern "C" __global__ __launch_bounds__(256, 4)
void attn_kernel(const __hip_bfloat16* __restrict__ qkb,
                 const __hip_bfloat16* __restrict__ vT,
                 __hip_bfloat16* __restrict__ attout) {
    __shared__ float sbuf[8256];                 // 33024 B: pb (bf16 16x1032) / redo union
    __shared__ float redm[4][16];
    __shared__ float reds[4][16];
    __hip_bfloat16 (*pb)[1032] = (__hip_bfloat16 (*)[1032])sbuf;
    float (*redo)[16][33] = (float (*)[16][33])sbuf;
    const int t = threadIdx.x;
    const int qt = blockIdx.x, h = blockIdx.y, bb = blockIdx.z;
    const int q0 = qt * 16;
    const int lane = t & 63, wv = t >> 6;
    const int fr = lane & 15, g = lane >> 4;
    const int kbase = wv * 256;
    const float scale = 0.17677669529663687f;

    bf16x8 qfrag = *(const bf16x8*)(qkb + ((long long)(bb * NQ + q0 + fr)) * 512 + h * HD + g * 8);

    f32x4 sfr[16];
    #pragma unroll
    for (int half = 0; half < 2; ++half) {
        bf16x8 kf[8];
        #pragma unroll
        for (int j = 0; j < 8; ++j) {
            const int key0 = kbase + (half * 8 + j) * 16;
            kf[j] = *(const bf16x8*)(qkb + ((long long)(bb * NQ + key0 + fr)) * 512 + 256 + h * HD + g * 8);
        }
        __builtin_amdgcn_sched_barrier(0);
        #pragma unroll
        for (int j = 0; j < 8; ++j) {
            f32x4 z = {0.f, 0.f, 0.f, 0.f};
            sfr[half * 8 + j] = __builtin_amdgcn_mfma_f32_16x16x32_bf16(qfrag, kf[j], z, 0, 0, 0);
        }
    }
    #pragma unroll
    for (int kt = 0; kt < 16; ++kt)
        #pragma unroll
        for (int r = 0; r < 4; ++r) sfr[kt][r] *= scale;

    float mxr[4];
    #pragma unroll
    for (int r = 0; r < 4; ++r) {
        float mx = -1e30f;
        #pragma unroll
        for (int kt = 0; kt < 16; ++kt) mx = fmaxf(mx, sfr[kt][r]);
        #pragma unroll
        for (int mm = 1; mm <= 8; mm <<= 1) mx = fmaxf(mx, __shfl_xor(mx, mm, 64));
        float sm = 0.f;
        #pragma unroll
        for (int kt = 0; kt < 16; ++kt) {
            float e = __expf(sfr[kt][r] - mx);
            sfr[kt][r] = e;                 // keep e, rescale later
            sm += e;
        }
        #pragma unroll
        for (int mm = 1; mm <= 8; mm <<= 1) sm += __shfl_xor(sm, mm, 64);
        mxr[r] = mx;
        if (fr == 0) { redm[wv][4 * g + r] = mx; reds[wv][4 * g + r] = sm; }
    }
    __syncthreads();

    float scl[4];
    #pragma unroll
    for (int r = 0; r < 4; ++r) {
        const int q = 4 * g + r;
        float mm = fmaxf(fmaxf(redm[0][q], redm[1][q]), fmaxf(redm[2][q], redm[3][q]));
        float ll = 0.f;
        #pragma unroll
        for (int w2 = 0; w2 < 4; ++w2) ll += reds[w2][q] * __expf(redm[w2][q] - mm);
        scl[r] = __expf(mxr[r] - mm) / ll;   // e * scl == exp(s-gm)*gl
    }
    #pragma unroll
    for (int kt = 0; kt < 16; ++kt) {
        #pragma unroll
        for (int r = 0; r < 4; ++r) {
            pb[4 * g + r][kbase + kt * 16 + fr] = __float2bfloat16(sfr[kt][r] * scl[r]);
        }
    }

    f32x4 o0 = {0.f, 0.f, 0.f, 0.f}, o1 = {0.f, 0.f, 0.f, 0.f};
    const __hip_bfloat16* vbase = vT + ((long long)bb * DIM + h * HD) * 1024;
    #pragma unroll
    for (int ksb = 0; ksb < 2; ++ksb) {
        bf16x8 pf[4], v0[4], v1[4];
        #pragma unroll
        for (int j = 0; j < 4; ++j) {
            const int key0 = kbase + (ksb * 4 + j) * 32 + g * 8;
            pf[j] = *(const bf16x8*)&pb[fr][key0];
            v0[j] = *(const bf16x8*)(vbase + (long long)fr * 1024 + key0);
            v1[j] = *(const bf16x8*)(vbase + (long long)(16 + fr) * 1024 + key0);
        }
        __builtin_amdgcn_sched_barrier(0);
        #pragma unroll
        for (int j = 0; j < 4; ++j) {
            o0 = __builtin_amdgcn_mfma_f32_16x16x32_bf16(pf[j], v0[j], o0, 0, 0, 0);
            o1 = __builtin_amdgcn_mfma_f32_16x16x32_bf16(pf[j], v1[j], o1, 0, 0, 0);
        }
    }

    __syncthreads();   // all waves done reading pb before redo overwrites it
    #pragma unroll
    for (int r = 0; r < 4; ++r) {
        redo[wv][4 * g + r][fr] = o0[r];
        redo[wv][4 * g + r][16 + fr] = o1[r];
    }
    __syncthreads();
    #pragma unroll
    for (int i = 0; i < 2; ++i) {
        const int idx = t + i * 256;
        const int q = idx >> 5, d = idx & 31;
        float v = redo[0][q][d] + redo[1][q][d] + redo[2][q][d] + redo[3][q][d];
        attout[((long long)(bb * NQ + q0 + q)) * DIM + h * HD + d] = __float2bfloat16(v);
    }
}

// ---------------- residual + LayerNorm, fused epilogues ----------------
extern "C" __global__ __launch_bounds__(256)
void ln_kernel(const float* __restrict__ X, long long sx,
               const float* __restrict__ R, long long sr,
               const float* __restrict__ g, const float* __restrict__ bta,
               float* __restrict__ O, long long so,
               __hip_bfloat16* __restrict__ Ob,
               const float* __restrict__ P,
               __hip_bfloat16* __restrict__ Qb,
               const int* __restrict__ gidx,
               float* __restrict__ OG) {
    __shared__ float red[4];
    const int row = blockIdx.x, bb = blockIdx.y, t = threadIdx.x;
    float x = X[(long long)bb * sx + (long long)row * DIM + t]
            + R[(long long)bb * sr + (long long)row * DIM + t];
    float v = x;
    #pragma unroll
    for (int m = 32; m >= 1; m >>= 1) v += __shfl_xor(v, m, 64);
    if ((t & 63) == 0) red[t >> 6] = v;
    __syncthreads();
    float mean = (red[0] + red[1] + red[2] + red[3]) * (1.f / 256.f);
    __syncthreads();
    float d = x - mean;
    v = d * d;
    #pragma unroll
    for (int m = 32; m >= 1; m >>= 1) v += __shfl_xor(v, m, 64);
    if ((t & 63) == 0) red[t >> 6] = v;
    __syncthreads();
    float var = (red[0] + red[1] + red[2] + red[3]) * (1.f / 256.f);
    float o = d * rsqrtf(var + 1e-5f) * g[t] + bta[t];
    const long long ofs = (long long)bb * so + (long long)row * DIM + t;
    if (gidx) {
        const int i = gidx[bb * NSEL + row];
        OG[((long long)(bb * HW_N + i)) * DIM + t] = o;
    } else {
        O[ofs] = o;
        if (Ob) Ob[ofs] = __float2bfloat16(o);
        if (Qb) Qb[ofs] = __float2bfloat16(o + P[ofs]);
    }
}

// ---------------- box attention, L2-local (one head-plane per block) ----------
extern "C" __global__ __launch_bounds__(256)
void boxattn_kernel(const float* __restrict__ qout, const float* __restrict__ selref,
                    const __hip_bfloat16* __restrict__ vp, const float* __restrict__ kidx,
                    __hip_bfloat16* __restrict__ boxout) {
    __shared__ float aw_s[400];
    __shared__ float ob_s[64];
    __shared__ float ref_s[112];
    __shared__ float ki_s[50];
    __shared__ float dg_s[800];
    __shared__ float box_s[16][6];
    __shared__ float mx_s[16];
    __shared__ float inv_s[16];
    __shared__ float wq_s[400];
    __shared__ int   i4_s[1600];
    __shared__ float w4_s[1600];
    const int t = threadIdx.x;
    const int combo = blockIdx.x;            // b*8 + h
    const int bb = combo >> 3, h = combo & 7;
    const int s0 = blockIdx.y * 16;
    const long long base = (long long)bb * NSEL + s0;

    #pragma unroll
    for (int e = t; e < 400; e += 256) {
        const int s = e / 25, p = e - s * 25;
        aw_s[e] = qout[(base + s) * NQOUT + h * 25 + p];
    }
    if (t < 64)  ob_s[t] = qout[(base + (t >> 2)) * NQOUT + 200 + h * 4 + (t & 3)];
    if (t < 112) ref_s[t] = selref[base * 7 + t];
    if (t < 50)  ki_s[t] = kidx[t];
    #pragma unroll
    for (int e = t; e < 800; e += 256) {
        const int s = e / 50, r = e - s * 50;
        dg_s[e] = qout[(base + s) * NQOUT + 232 + h * 50 + r];
    }
    __syncthreads();

    if (t < 16) {
        float mx = -1e30f;
        #pragma unroll
        for (int p = 0; p < NP_; ++p) mx = fmaxf(mx, aw_s[t * NP_ + p]);
        mx_s[t] = mx;
        const float r0 = ref_s[t * 7 + 0], r1 = ref_s[t * 7 + 1];
        const float r3 = ref_s[t * 7 + 3], r4 = ref_s[t * 7 + 4], r6 = ref_s[t * 7 + 6];
        box_s[t][0] = r0 + ob_s[t * 4 + 0] * 0.125f * r3;
        box_s[t][1] = r1 + ob_s[t * 4 + 1] * 0.125f * r4;
        box_s[t][2] = fmaxf(r3 + ob_s[t * 4 + 2] * 0.125f * r3, 0.f);
        box_s[t][3] = fmaxf(r4 + ob_s[t * 4 + 3] * 0.125f * r4, 0.f);
        box_s[t][4] = cosf(r6);
        box_s[t][5] = sinf(r6);
    }
    __syncthreads();

    #pragma unroll
    for (int e = t; e < 400; e += 256) {
        const int s = e / 25, p = e - s * 25;
        const float w = __expf(aw_s[e] - mx_s[s]);
        wq_s[e] = w;
        const float cx = box_s[s][0], cy = box_s[s][1];
        const float sw = box_s[s][2], sh = box_s[s][3];
        const float ca = box_s[s][4], sa = box_s[s][5];
        const float fx = ki_s[p * 2 + 0] * sw;
        const float fy = ki_s[p * 2 + 1] * sh;
        const float gx = cx + ca * fx - sa * fy + dg_s[s * 50 + 2 * p + 0] * (1.f / 188.f);
        const float gy = cy + sa * fx + ca * fy + dg_s[s * 50 + 2 * p + 1] * (1.f / 188.f);
        const float x = gx * 128.f - 0.5f;
        const float y = gy * 128.f - 0.5f;
        const float x0f = floorf(x), y0f = floorf(y);
        const float lx = x - x0f, ly = y - y0f;
        const int x0 = (int)x0f, y0 = (int)y0f;
        #pragma unroll
        for (int c = 0; c < 4; ++c) {
            const int xi = x0 + (c & 1);
            const int yi = y0 + (c >> 1);
            const float wgt = ((c & 1) ? lx : 1.f - lx) * ((c >> 1) ? ly : 1.f - ly);
            const bool valid = (xi >= 0) & (xi < 128) & (yi >= 0) & (yi < 128);
            const int cxi = min(max(xi, 0), 127);
            const int cyi = min(max(yi, 0), 127);
            i4_s[e * 4 + c] = cyi * 128 + cxi;
            w4_s[e * 4 + c] = w * (valid ? wgt : 0.f);
        }
    }
    __syncthreads();

    if (t < 16) {
        float sm = 0.f;
        #pragma unroll
        for (int p = 0; p < NP_; ++p) sm += wq_s[t * NP_ + p];
        inv_s[t] = 1.f / sm;
    }

    {
        const int lane = t & 63;
        const int s_loc = t >> 4;
        const int j2 = (lane >> 2) & 3;
        const int q2 = lane & 3;
        const __hip_bfloat16* vb = vp + ((long long)(bb * 8 + h) * 16384) * 32 + q2 * 8;
        const int ebase = s_loc * 100;
        float a[8] = {0.f, 0.f, 0.f, 0.f, 0.f, 0.f, 0.f, 0.f};
        #pragma unroll
        for (int u = 0; u < 25; ++u) {
            const int ii = ebase + j2 + 4 * u;
            bf16x8 v = *(const bf16x8*)(vb + (long long)i4_s[ii] * 32);
            const float w = w4_s[ii];
            #pragma unroll
            for (int k = 0; k < 8; ++k) a[k] += w * (float)v[k];
        }
        #pragma unroll
        for (int k = 0; k < 8; ++k) a[k] += __shfl_xor(a[k], 4, 64);
        #pragma unroll
        for (int k = 0; k < 8; ++k) a[k] += __shfl_xor(a[k], 8, 64);
        __syncthreads();
        if (j2 == 0) {
            const float inv = inv_s[s_loc];
            __hip_bfloat16* op = boxout + (base + s_loc) * DIM + h * HD + q2 * 8;
            bf16x8 o;
            #pragma unroll
            for (int k = 0; k < 8; ++k) o[k] = __float2bfloat16(a[k] * inv);
            *(bf16x8*)op = o;
        }
    }
}

extern "C" void kernel_launch(void* const* d_in, const int* in_sizes, int n_in,
                              void* d_out, int out_size, void* d_ws, size_t ws_size,
                              hipStream_t stream) {
    const float* src          = (const float*)d_in[0];
    const float* pos          = (const float*)d_in[1];
    const float* refw         = (const float*)d_in[4];
    const float* score        = (const float*)d_in[5];
    const float* in_proj_w    = (const float*)d_in[6];
    const float* in_proj_b    = (const float*)d_in[7];
    const float* mha_out_w    = (const float*)d_in[8];
    const float* mha_out_b    = (const float*)d_in[9];
    const float* value_proj_w = (const float*)d_in[10];
    const float* value_proj_b = (const float*)d_in[11];
    const float* lin_attn_w   = (const float*)d_in[12];
    const float* lin_attn_b   = (const float*)d_in[13];
    const float* lin_box_w    = (const float*)d_in[14];
    const float* lin_box_b    = (const float*)d_in[15];
    const float* samp_off_w   = (const float*)d_in[16];
    const float* samp_off_b   = (const float*)d_in[17];
    const float* ca_out_w     = (const float*)d_in[18];
    const float* ca_out_b     = (const float*)d_in[19];
    const float* lin1_w       = (const float*)d_in[20];
    const float* lin1_b       = (const float*)d_in[21];
    const float* lin2_w       = (const float*)d_in[22];
    const float* lin2_b       = (const float*)d_in[23];
    const float* qn_g         = (const float*)d_in[24];
    const float* qn_b         = (const float*)d_in[25];
    const float* n1_g         = (const float*)d_in[26];
    const float* n1_b         = (const float*)d_in[27];
    const float* n2_g         = (const float*)d_in[28];
    const float* n2_b         = (const float*)d_in[29];
    const float* kidx         = (const float*)d_in[30];

    float* w = (float*)d_ws;
    int* idxp = (int*)d_ws;
    float* selref = w + OFF_SELREF;
    float* selsrc = w + OFF_SELSRC;
    float* selpos = w + OFF_SELPOS;
    __hip_bfloat16* boxoutb = (__hip_bfloat16*)(w + OFF_SELPOS);  // reuse after selpos dead
    __hip_bfloat16* queryb  = (__hip_bfloat16*)(w + OFF_QUERY);   // bf16 query
    float* src2   = w + OFF_QUERY;    // reuse after queryb dead
    __hip_bfloat16* vproj  = (__hip_bfloat16*)(w + OFF_BIG);   // head-planar bf16
    __hip_bfloat16* ffntb  = (__hip_bfloat16*)(w + OFF_BIG);   // reuse after vproj dead
    __hip_bfloat16* wbf    = (__hip_bfloat16*)(w + OFF_WBF);   // bf16 weight pool
    float* qbias  = w + OFF_QBIAS;                              // packed 632-float bias
    __hip_bfloat16* qkbin   = (__hip_bfloat16*)(w + OFF_F);            // qk bf16 (A of qkv gemm)
    __hip_bfloat16* selsrcb = (__hip_bfloat16*)(w + OFF_F + 262144);   // selsrc bf16 rows 0..NQ
    __hip_bfloat16* qkb = (__hip_bfloat16*)(w + OFF_F + 524288);       // qkv gemm out
    __hip_bfloat16* vT  = (__hip_bfloat16*)(w + OFF_F + 1572864);
    __hip_bfloat16* attoutb = (__hip_bfloat16*)(w + OFF_F + 2097152);  // attn out bf16
    float* q2     = w + OFF_F + 2621440;
    float* qout   = w + OFF_F;              // fused query-GEMM out [2*4096][632] (reuse after MHA dead)
    float* ff     = w + OFF_F;              // reuse after box-attn dead
    __hip_bfloat16* selsrcb2 = (__hip_bfloat16*)(w + OFF_F + 1048576); // n1-LN bf16 out (A of lin1)
    unsigned int* hist2 = (unsigned int*)(w + OFF_F);          // topk scratch
    unsigned int* ctrl2 = hist2 + 16384;
    unsigned long long* list1 = (unsigned long long*)(hist2 + 16448);
    unsigned long long* list2 = list1 + 2 * 2048;
    float* out    = (float*)d_out;

    // bf16 weight pool offsets (W_LATTN..W_SOFF are CONTIGUOUS -> fused [632][256])
    const long long W_INPROJ = 0, W_MHAOUT = 196608, W_VALUE = 262144,
                    W_LATTN = 327680, W_LBOX = 378880, W_SOFF = 387072,
                    W_CAOUT = 489472, W_LIN1 = 555008, W_LIN2 = 817152;

    hipMemcpyAsync(d_out, src, (size_t)2 * HW_N * DIM * sizeof(float),
                   hipMemcpyDeviceToDevice, stream);

    wcvt_kernel<<<4216, 256, 0, stream>>>(in_proj_w, mha_out_w, value_proj_w,
                                          lin_attn_w, lin_box_w, samp_off_w,
                                          ca_out_w, lin1_w, lin2_w, wbf);
    qbias_kernel<<<3, 256, 0, stream>>>(lin_attn_b, lin_box_b, samp_off_b, qbias);

    hipMemsetAsync(hist2, 0, 16448 * sizeof(unsigned int), stream);
    topk_hist_kernel<<<dim3(32, 2), 512, 0, stream>>>(score, hist2);
    topk_scan_kernel<<<2, 1024, 0, stream>>>(hist2, ctrl2);
    topk_collect_kernel<<<dim3(16, 2), 1024, 0, stream>>>(score, ctrl2, list1, list2);
    topk_classify_kernel<<<dim3(16, 2), 1024, 0, stream>>>(score, ctrl2, list1, list2, idxp);

    gather_kernel<<<dim3(NSEL, 2), 256, 0, stream>>>(src, pos, refw, idxp,
                                                     selsrc, selpos, selref,
                                                     qkbin, selsrcb, queryb);
    // fused in_proj: qkv (N=512) + vT (N=256) in one 384-block launch
    gemm_dual_kernel<<<dim3(12, 16, 2), 256, 0, stream>>>(qkbin, selsrcb, wbf + W_INPROJ,
                                                          in_proj_b, qkb, vT);
    attn_kernel<<<dim3(64, 8, 2), 256, 0, stream>>>(qkb, vT, attoutb);
    gemm_kernel<<<dim3(4, 16, 2), 256, 0, stream>>>(attoutb, 262144LL, wbf + W_MHAOUT, mha_out_b,
                                                    q2, 262144LL, NQ, 256, 256, 0, 0, 1);
    // qn-LN fused with addq: queryb rows [0,NQ) = bf16(ln_out + selpos)
    ln_kernel<<<dim3(NQ, 2), 256, 0, stream>>>(selsrc, 1048576LL, q2, 262144LL,
                                               qn_g, qn_b, selsrc, 1048576LL,
                                               nullptr, selpos, queryb, nullptr, nullptr);
    // vproj: 128^2-tile GEMM (M=16384, N=256, K=256), fp32 A, head-planar out
    gemm128r_kernel<<<dim3(2, 128, 2), 256, 0, stream>>>(src, 4194304LL, wbf + W_VALUE, value_proj_b,
                                                         (float*)vproj, 4194304LL, HW_N, 256, 256, 0, 3, 0);
    // fused query GEMM: [aw | ob | dgrid] = query @ [W_LATTN;W_LBOX;W_SOFF]^T + qbias
    gemm_kernel<<<dim3(10, 64, 2), 256, 0, stream>>>(queryb, 1048576LL, wbf + W_LATTN, qbias,
                                                     qout, (long long)NSEL * NQOUT,
                                                     NSEL, NQOUT, 256, 0, 0, 1);
    boxattn_kernel<<<dim3(16, 256), 256, 0, stream>>>(qout, selref, vproj, kidx, boxoutb);
    gemm_kernel<<<dim3(4, 64, 2), 256, 0, stream>>>(boxoutb, 1048576LL, wbf + W_CAOUT, ca_out_b,
                                                    src2, 1048576LL, NSEL, 256, 256, 0, 0, 1);
    ln_kernel<<<dim3(NSEL, 2), 256, 0, stream>>>(selsrc, 1048576LL, src2, 1048576LL,
                                                 n1_g, n1_b, selsrc, 1048576LL,
                                                 selsrcb2, nullptr, nullptr, nullptr, nullptr);
    // lin1: 128^2 tile (M=4096, N=1024, K=256), bf16 A, relu, bf16 out
    gemm128r_kernel<<<dim3(8, 32, 2), 256, 0, stream>>>(selsrcb2, 1048576LL, wbf + W_LIN1, lin1_b,
                                                        (float*)ffntb, 4194304LL, NSEL, DFF_, 256, 1, 1, 1);
    // lin2: 128^2 tile (M=4096, N=256, K=1024), bf16 A, fp32 out
    gemm128r_kernel<<<dim3(2, 32, 2), 256, 0, stream>>>(ffntb, 4194304LL, wbf + W_LIN2, lin2_b,
                                                        ff, 1048576LL, NSEL, 256, DFF_, 0, 0, 1);
    // n2-LN fused with scatter: write directly to out[idx]
    ln_kernel<<<dim3(NSEL, 2), 256, 0, stream>>>(selsrc, 1048576LL, ff, 1048576LL,
                                                 n2_g, n2_b, nullptr, 1048576LL,
                                                 nullptr, nullptr, nullptr, idxp, out);
}

// Round 13
// 381.174 us; speedup vs baseline: 1.0396x; 1.0396x over previous
//
#include <hip/hip_runtime.h>
#include <hip/hip_bf16.h>
#include <math.h>

// Problem constants
#define HW_N   16384
#define DIM    256
#define NSEL   4096
#define NQ     1024
#define NHEAD  8
#define HD     32
#define NP_    25
#define DFF_   1024
#define NQOUT  632    // fused query-GEMM output width (200 aw | 32 ob | 400 dgrid)

// Workspace layout (float offsets). ~96 MB total (guarded by ws_size).
#define OFF_SELREF  8448LL          // 2*4096*7
#define OFF_SELSRC  65792LL         // 2*4096*256
#define OFF_SELPOS  2162944LL       // 2*4096*256 (later reused as boxout bf16)
#define OFF_QUERY   4260096LL       // 2*4096*256 (query bf16, later src2 fp32)
#define OFF_BIG     6357248LL       // vproj bf16 [0,4194304) then ffnt bf16 same slot
#define OFF_WBF     10551552LL      // OFF_BIG+4194304: bf16 weights, 1079296 bf16
#define OFF_QBIAS   11151552LL      // packed query bias, 632 floats (inside WBF region slack)
#define OFF_F       14745856LL      // multi-use region, 5177344 floats
#define OFF_SRCB    19923200LL      // bf16 copy of src, 4194304 floats worth (16.8MB)
#define WS_NEED_B   ((OFF_SRCB + 2097152LL) * 4LL)   // ~88 MB (srcb = 8.4M bf16 = 2.1M floats... use full)
#define WS_NEED_B2  ((OFF_SRCB + 4194304LL) * 4LL)   // 96.5 MB safe bound

__device__ __forceinline__ unsigned int f2s(float f) {
    unsigned int u = __float_as_uint(f);
    return (u & 0x80000000u) ? ~u : (u | 0x80000000u);
}

typedef __bf16 bf16x8 __attribute__((ext_vector_type(8)));
typedef __bf16 bf16x4 __attribute__((ext_vector_type(4)));
typedef float  f32x4  __attribute__((ext_vector_type(4)));

// ============ weight preconversion + query-bias packing ============
// Blocks [0,4216): convert 9 fp32 matrices -> one bf16 pool.
// Block 4216: pack [lin_attn_b | lin_box_b | samp_off_b] into qbias (632 floats).
extern "C" __global__ __launch_bounds__(256)
void wcvt_kernel(const float* __restrict__ s0, const float* __restrict__ s1,
                 const float* __restrict__ s2, const float* __restrict__ s3,
                 const float* __restrict__ s4, const float* __restrict__ s5,
                 const float* __restrict__ s6, const float* __restrict__ s7,
                 const float* __restrict__ s8, __hip_bfloat16* __restrict__ dst,
                 const float* __restrict__ qb_a, const float* __restrict__ qb_b,
                 const float* __restrict__ qb_c, float* __restrict__ qbias) {
    if (blockIdx.x == 4216) {
        for (int e = threadIdx.x; e < 632; e += 256) {
            float v;
            if (e < 200)      v = qb_a[e];
            else if (e < 232) v = qb_b[e - 200];
            else              v = qb_c[e - 232];
            qbias[e] = v;
        }
        return;
    }
    const long long g = (long long)blockIdx.x * 256 + threadIdx.x;
    const float* s; long long base;
    if      (g < 196608)  { s = s0; base = 0; }
    else if (g < 262144)  { s = s1; base = 196608; }
    else if (g < 327680)  { s = s2; base = 262144; }
    else if (g < 378880)  { s = s3; base = 327680; }
    else if (g < 387072)  { s = s4; base = 378880; }
    else if (g < 489472)  { s = s5; base = 387072; }
    else if (g < 555008)  { s = s6; base = 489472; }
    else if (g < 817152)  { s = s7; base = 555008; }
    else                  { s = s8; base = 817152; }
    dst[g] = __float2bfloat16(s[g - base]);
}

// ============ src fp32 -> bf16 (A-operand of vproj) ============
extern "C" __global__ __launch_bounds__(256)
void scvt_kernel(const float* __restrict__ s, __hip_bfloat16* __restrict__ d) {
    const long long i = ((long long)blockIdx.x * 256 + threadIdx.x) * 8;
    float4 v0 = *(const float4*)(s + i);
    float4 v1 = *(const float4*)(s + i + 4);
    bf16x8 o;
    o[0] = __float2bfloat16(v0.x); o[1] = __float2bfloat16(v0.y);
    o[2] = __float2bfloat16(v0.z); o[3] = __float2bfloat16(v0.w);
    o[4] = __float2bfloat16(v1.x); o[5] = __float2bfloat16(v1.y);
    o[6] = __float2bfloat16(v1.z); o[7] = __float2bfloat16(v1.w);
    *(bf16x8*)(d + i) = o;
}

// ================= top-k, grid-parallel (4 kernels) =================
extern "C" __global__ __launch_bounds__(512)
void topk_hist_kernel(const float* __restrict__ score, unsigned int* __restrict__ hist) {
    const int t = threadIdx.x, bx = blockIdx.x, bb = blockIdx.y;
    const int i = bx * 512 + t;
    unsigned int u = f2s(score[(long long)bb * HW_N + i]);
    atomicAdd(&hist[bb * 8192 + (u >> 19)], 1u);
}

extern "C" __global__ __launch_bounds__(1024)
void topk_scan_kernel(const unsigned int* __restrict__ hist, unsigned int* __restrict__ ctrl) {
    __shared__ unsigned int scan[1024];
    const int t = threadIdx.x, bb = blockIdx.x;
    unsigned int loc[8]; unsigned int lsum = 0u;
    #pragma unroll
    for (int k = 0; k < 8; ++k) { loc[k] = hist[bb * 8192 + t * 8 + k]; lsum += loc[k]; }
    scan[t] = lsum;
    __syncthreads();
    for (int off = 1; off < 1024; off <<= 1) {
        unsigned int v = (t + off < 1024) ? scan[t + off] : 0u;
        __syncthreads();
        scan[t] += v;
        __syncthreads();
    }
    unsigned int nxt = (t < 1023) ? scan[t + 1] : 0u;
    unsigned int run = nxt;
    for (int k = 7; k >= 0; --k) {
        run += loc[k];
        unsigned int above = run - loc[k];
        if (run >= 1024u && above < 1024u) { ctrl[bb * 16 + 0] = (unsigned)(t * 8 + k); ctrl[bb * 16 + 1] = 1024u - above; }
        if (run >= 4096u && above < 4096u) { ctrl[bb * 16 + 2] = (unsigned)(t * 8 + k); ctrl[bb * 16 + 3] = 4096u - above; }
    }
}

extern "C" __global__ __launch_bounds__(1024)
void topk_collect_kernel(const float* __restrict__ score, unsigned int* __restrict__ ctrl,
                         unsigned long long* __restrict__ list1,
                         unsigned long long* __restrict__ list2) {
    const int t = threadIdx.x, bx = blockIdx.x, bb = blockIdx.y;
    const int i = bx * 1024 + t;
    const unsigned int T1 = ctrl[bb * 16 + 0], T2 = ctrl[bb * 16 + 2];
    unsigned int u = f2s(score[(long long)bb * HW_N + i]);
    unsigned int bin = u >> 19;
    unsigned long long key = ((unsigned long long)u << 32) | (unsigned int)(~(unsigned int)i);
    if (bin == T1) {
        unsigned int p = atomicAdd(&ctrl[bb * 16 + 4], 1u);
        if (p < 2048u) list1[bb * 2048 + p] = key;
    }
    if (bin == T2 && T2 != T1) {
        unsigned int p = atomicAdd(&ctrl[bb * 16 + 5], 1u);
        if (p < 2048u) list2[bb * 2048 + p] = key;
    }
}

extern "C" __global__ __launch_bounds__(1024)
void topk_classify_kernel(const float* __restrict__ score, unsigned int* __restrict__ ctrl,
                          const unsigned long long* __restrict__ list1,
                          const unsigned long long* __restrict__ list2,
                          int* __restrict__ idx_out) {
    __shared__ unsigned int cA, cB, baseA, baseB;
    const int t = threadIdx.x, bx = blockIdx.x, bb = blockIdx.y;
    const int i = bx * 1024 + t;
    if (t == 0) { cA = 0u; cB = 0u; }
    __syncthreads();
    const unsigned int T1 = ctrl[bb * 16 + 0], need1 = ctrl[bb * 16 + 1];
    const unsigned int T2 = ctrl[bb * 16 + 2], need2 = ctrl[bb * 16 + 3];
    const unsigned int c1 = min(ctrl[bb * 16 + 4], 2048u);
    const unsigned int c2 = min(ctrl[bb * 16 + 5], 2048u);
    unsigned int u = f2s(score[(long long)bb * HW_N + i]);
    unsigned int bin = u >> 19;
    unsigned long long key = ((unsigned long long)u << 32) | (unsigned int)(~(unsigned int)i);
    bool inA = false, inB = false;
    if (bin > T1) {
        inA = true;
    } else if (bin == T1) {
        unsigned int r = 0;
        for (unsigned int q = 0; q < c1; ++q) r += (list1[bb * 2048 + q] > key) ? 1u : 0u;
        if (r < need1) inA = true;
        else if (T2 == T1) inB = (r < need2);
        else inB = true;
    } else if (bin > T2) {
        inB = true;
    } else if (bin == T2) {
        unsigned int r = 0;
        for (unsigned int q = 0; q < c2; ++q) r += (list2[bb * 2048 + q] > key) ? 1u : 0u;
        inB = (r < need2);
    }
    unsigned int sA = 0u, sB = 0u;
    if (inA) sA = atomicAdd(&cA, 1u);
    if (inB) sB = atomicAdd(&cB, 1u);
    __syncthreads();
    if (t == 0) {
        baseA = atomicAdd(&ctrl[bb * 16 + 6], cA);
        baseB = atomicAdd(&ctrl[bb * 16 + 7], cB);
    }
    __syncthreads();
    if (inA) idx_out[bb * NSEL + baseA + sA] = i;
    if (inB) idx_out[bb * NSEL + 1024 + baseB + sB] = i;
}

// ---------------- gather selected rows (+ bf16 copies for MFMA A-operands) ----
extern "C" __global__ __launch_bounds__(256)
void gather_kernel(const float* __restrict__ src, const float* __restrict__ pos,
                   const float* __restrict__ refw, const int* __restrict__ idx,
                   float* __restrict__ selsrc, float* __restrict__ selpos,
                   float* __restrict__ selref,
                   __hip_bfloat16* __restrict__ qkb16,
                   __hip_bfloat16* __restrict__ selsrcb,
                   __hip_bfloat16* __restrict__ queryb) {
    const int s = blockIdx.x, bb = blockIdx.y, t = threadIdx.x;
    const int i = idx[bb * NSEL + s];
    const long long so = ((long long)(bb * NSEL + s)) * DIM;
    const long long go = ((long long)(bb * HW_N + i)) * DIM;
    float sv = src[go + t], pv = pos[go + t];
    selsrc[so + t] = sv;
    selpos[so + t] = pv;
    if (s < NQ) {
        const long long qo = ((long long)(bb * NQ + s)) * DIM + t;
        qkb16[qo] = __float2bfloat16(sv + pv);
        selsrcb[qo] = __float2bfloat16(sv);
    } else {
        queryb[so + t] = __float2bfloat16(sv + pv);
    }
    if (t < 7)
        selref[(long long)(bb * NSEL + s) * 7 + t] = refw[(long long)(bb * HW_N + i) * 7 + t];
}

// ---------------- bf16 MFMA GEMM (64x64 tile): C = act(A @ W^T + bias) --------
extern "C" __global__ __launch_bounds__(256)
void gemm_kernel(const void* __restrict__ Avp, long long sA,
                 const __hip_bfloat16* __restrict__ W, const float* __restrict__ bias,
                 float* __restrict__ C, long long sC,
                 int M, int N, int K, int relu, int omode, int amode) {
    __shared__ __hip_bfloat16 As[64][72];
    __shared__ __hip_bfloat16 Ws[64][72];
    const int t = threadIdx.x;
    const int n0 = blockIdx.x * 64, m0 = blockIdx.y * 64;
    const long long zoff = (long long)blockIdx.z * sC;
    const int lane = t & 63, wv = t >> 6;
    const int mw = (wv >> 1) * 32, nw = (wv & 1) * 32;
    const int fr = lane & 15;
    const int fk = (lane >> 4) * 8;
    const int sr = t >> 2;
    const int sk = (t & 3) * 16;

    f32x4 acc[2][2];
    #pragma unroll
    for (int i = 0; i < 2; ++i)
        #pragma unroll
        for (int j = 0; j < 2; ++j) acc[i][j] = {0.f, 0.f, 0.f, 0.f};

    const bool wok = (n0 + sr) < N;
    for (int k0 = 0; k0 < K; k0 += 64) {
        uint4 wa = make_uint4(0u, 0u, 0u, 0u), wb = make_uint4(0u, 0u, 0u, 0u);
        if (wok) {
            const __hip_bfloat16* wp = W + (long long)(n0 + sr) * K + k0 + sk;
            wa = *(const uint4*)wp;
            wb = *(const uint4*)(wp + 8);
        }
        if (amode) {
            const __hip_bfloat16* ap = (const __hip_bfloat16*)Avp
                + (long long)blockIdx.z * sA + (long long)(m0 + sr) * K + k0 + sk;
            uint4 aa = *(const uint4*)ap;
            uint4 ab = *(const uint4*)(ap + 8);
            __syncthreads();
            *(uint4*)&As[sr][sk] = aa;
            *(uint4*)&As[sr][sk + 8] = ab;
            *(uint4*)&Ws[sr][sk] = wa;
            *(uint4*)&Ws[sr][sk + 8] = wb;
        } else {
            const float* ap = (const float*)Avp
                + (long long)blockIdx.z * sA + (long long)(m0 + sr) * K + k0 + sk;
            float av[16];
            #pragma unroll
            for (int q = 0; q < 4; ++q) {
                float4 v = *(const float4*)(ap + q * 4);
                av[q * 4 + 0] = v.x; av[q * 4 + 1] = v.y; av[q * 4 + 2] = v.z; av[q * 4 + 3] = v.w;
            }
            __syncthreads();
            #pragma unroll
            for (int q = 0; q < 16; ++q) As[sr][sk + q] = __float2bfloat16(av[q]);
            *(uint4*)&Ws[sr][sk] = wa;
            *(uint4*)&Ws[sr][sk + 8] = wb;
        }
        __syncthreads();
        #pragma unroll
        for (int kk = 0; kk < 64; kk += 32) {
            bf16x8 a0 = *(const bf16x8*)&As[mw + fr][kk + fk];
            bf16x8 a1 = *(const bf16x8*)&As[mw + 16 + fr][kk + fk];
            bf16x8 b0 = *(const bf16x8*)&Ws[nw + fr][kk + fk];
            bf16x8 b1 = *(const bf16x8*)&Ws[nw + 16 + fr][kk + fk];
            acc[0][0] = __builtin_amdgcn_mfma_f32_16x16x32_bf16(a0, b0, acc[0][0], 0, 0, 0);
            acc[0][1] = __builtin_amdgcn_mfma_f32_16x16x32_bf16(a0, b1, acc[0][1], 0, 0, 0);
            acc[1][0] = __builtin_amdgcn_mfma_f32_16x16x32_bf16(a1, b0, acc[1][0], 0, 0, 0);
            acc[1][1] = __builtin_amdgcn_mfma_f32_16x16x32_bf16(a1, b1, acc[1][1], 0, 0, 0);
        }
    }
    const int crow = (lane >> 4) * 4;
    #pragma unroll
    for (int mi = 0; mi < 2; ++mi) {
        #pragma unroll
        for (int ni = 0; ni < 2; ++ni) {
            const int col = n0 + nw + ni * 16 + fr;
            if (col < N) {
                const float bv = bias ? bias[col] : 0.f;
                #pragma unroll
                for (int r = 0; r < 4; ++r) {
                    const int row = m0 + mw + mi * 16 + crow + r;
                    float v = acc[mi][ni][r] + bv;
                    if (relu) v = fmaxf(v, 0.f);
                    if (omode == 0) {
                        C[zoff + (long long)row * N + col] = v;
                    } else if (omode == 1) {
                        ((__hip_bfloat16*)C)[zoff + (long long)row * N + col] = __float2bfloat16(v);
                    } else if (omode == 2) {
                        ((__hip_bfloat16*)C)[zoff + (long long)col * M + row] = __float2bfloat16(v);
                    } else {
                        ((__hip_bfloat16*)C)[zoff + ((long long)(col >> 5) * 16384 + row) * 32 + (col & 31)]
                            = __float2bfloat16(v);
                    }
                }
            }
        }
    }
}

// ---------------- dual in_proj GEMM: qkv (N=512) + vT (N=256, transposed) -----
extern "C" __global__ __launch_bounds__(256)
void gemm_dual_kernel(const __hip_bfloat16* __restrict__ A1,
                      const __hip_bfloat16* __restrict__ A2,
                      const __hip_bfloat16* __restrict__ W,
                      const float* __restrict__ bias,
                      __hip_bfloat16* __restrict__ C1,
                      __hip_bfloat16* __restrict__ C2) {
    __shared__ __hip_bfloat16 As[64][72];
    __shared__ __hip_bfloat16 Ws[64][72];
    const int t = threadIdx.x;
    const bool p2 = (blockIdx.x >= 8);
    const int n0 = (p2 ? (blockIdx.x - 8) : blockIdx.x) * 64;
    const int m0 = blockIdx.y * 64;
    const int z = blockIdx.z;
    const __hip_bfloat16* A  = (p2 ? A2 : A1) + (long long)z * (NQ * DIM);
    const __hip_bfloat16* Wp = W + (p2 ? 512 * 256 : 0);
    const float* bp = bias + (p2 ? 512 : 0);
    const int lane = t & 63, wv = t >> 6;
    const int mw = (wv >> 1) * 32, nw = (wv & 1) * 32;
    const int fr = lane & 15;
    const int fk = (lane >> 4) * 8;
    const int sr = t >> 2;
    const int sk = (t & 3) * 16;

    f32x4 acc[2][2];
    #pragma unroll
    for (int i = 0; i < 2; ++i)
        #pragma unroll
        for (int j = 0; j < 2; ++j) acc[i][j] = {0.f, 0.f, 0.f, 0.f};

    for (int k0 = 0; k0 < 256; k0 += 64) {
        const __hip_bfloat16* wp = Wp + (long long)(n0 + sr) * 256 + k0 + sk;
        uint4 wa = *(const uint4*)wp;
        uint4 wb = *(const uint4*)(wp + 8);
        const __hip_bfloat16* ap = A + (long long)(m0 + sr) * 256 + k0 + sk;
        uint4 aa = *(const uint4*)ap;
        uint4 ab = *(const uint4*)(ap + 8);
        __syncthreads();
        *(uint4*)&As[sr][sk] = aa;
        *(uint4*)&As[sr][sk + 8] = ab;
        *(uint4*)&Ws[sr][sk] = wa;
        *(uint4*)&Ws[sr][sk + 8] = wb;
        __syncthreads();
        #pragma unroll
        for (int kk = 0; kk < 64; kk += 32) {
            bf16x8 a0 = *(const bf16x8*)&As[mw + fr][kk + fk];
            bf16x8 a1 = *(const bf16x8*)&As[mw + 16 + fr][kk + fk];
            bf16x8 b0 = *(const bf16x8*)&Ws[nw + fr][kk + fk];
            bf16x8 b1 = *(const bf16x8*)&Ws[nw + 16 + fr][kk + fk];
            acc[0][0] = __builtin_amdgcn_mfma_f32_16x16x32_bf16(a0, b0, acc[0][0], 0, 0, 0);
            acc[0][1] = __builtin_amdgcn_mfma_f32_16x16x32_bf16(a0, b1, acc[0][1], 0, 0, 0);
            acc[1][0] = __builtin_amdgcn_mfma_f32_16x16x32_bf16(a1, b0, acc[1][0], 0, 0, 0);
            acc[1][1] = __builtin_amdgcn_mfma_f32_16x16x32_bf16(a1, b1, acc[1][1], 0, 0, 0);
        }
    }
    const int crow = (lane >> 4) * 4;
    #pragma unroll
    for (int mi = 0; mi < 2; ++mi) {
        #pragma unroll
        for (int ni = 0; ni < 2; ++ni) {
            const int col = n0 + nw + ni * 16 + fr;
            const float bv = bp[col];
            #pragma unroll
            for (int r = 0; r < 4; ++r) {
                const int row = m0 + mw + mi * 16 + crow + r;
                float v = acc[mi][ni][r] + bv;
                if (!p2) {
                    C1[(long long)z * (NQ * 512) + (long long)row * 512 + col] = __float2bfloat16(v);
                } else {
                    C2[(long long)z * (NQ * 256) + (long long)col * NQ + row] = __float2bfloat16(v);
                }
            }
        }
    }
}

// ---------------- MHA via MFMA: 16 queries/block, S & softmax in registers ----
extern "C" __global__ __launch_bounds__(256, 4)
void attn_kernel(const __hip_bfloat16* __restrict__ qkb,
                 const __hip_bfloat16* __restrict__ vT,
                 __hip_bfloat16* __restrict__ attout) {
    __shared__ float sbuf[8256];                 // 33024 B: pb (bf16 16x1032) / redo union
    __shared__ float redm[4][16];
    __shared__ float reds[4][16];
    __hip_bfloat16 (*pb)[1032] = (__hip_bfloat16 (*)[1032])sbuf;
    float (*redo)[16][33] = (float (*)[16][33])sbuf;
    const int t = threadIdx.x;
    const int qt = blockIdx.x, h = blockIdx.y, bb = blockIdx.z;
    const int q0 = qt * 16;
    const int lane = t & 63, wv = t >> 6;
    const int fr = lane & 15, g = lane >> 4;
    const int kbase = wv * 256;
    const float scale = 0.17677669529663687f;

    bf16x8 qfrag = *(const bf16x8*)(qkb + ((long long)(bb * NQ + q0 + fr)) * 512 + h * HD + g * 8);

    f32x4 sfr[16];
    #pragma unroll
    for (int half = 0; half < 2; ++half) {
        bf16x8 kf[8];
        #pragma unroll
        for (int j = 0; j < 8; ++j) {
            const int key0 = kbase + (half * 8 + j) * 16;
            kf[j] = *(const bf16x8*)(qkb + ((long long)(bb * NQ + key0 + fr)) * 512 + 256 + h * HD + g * 8);
        }
        __builtin_amdgcn_sched_barrier(0);
        #pragma unroll
        for (int j = 0; j < 8; ++j) {
            f32x4 z = {0.f, 0.f, 0.f, 0.f};
            sfr[half * 8 + j] = __builtin_amdgcn_mfma_f32_16x16x32_bf16(qfrag, kf[j], z, 0, 0, 0);
        }
    }
    #pragma unroll
    for (int kt = 0; kt < 16; ++kt)
        #pragma unroll
        for (int r = 0; r < 4; ++r) sfr[kt][r] *= scale;

    float mxr[4];
    #pragma unroll
    for (int r = 0; r < 4; ++r) {
        float mx = -1e30f;
        #pragma unroll
        for (int kt = 0; kt < 16; ++kt) mx = fmaxf(mx, sfr[kt][r]);
        #pragma unroll
        for (int mm = 1; mm <= 8; mm <<= 1) mx = fmaxf(mx, __shfl_xor(mx, mm, 64));
        float sm = 0.f;
        #pragma unroll
        for (int kt = 0; kt < 16; ++kt) {
            float e = __expf(sfr[kt][r] - mx);
            sfr[kt][r] = e;                 // keep e, rescale later
            sm += e;
        }
        #pragma unroll
        for (int mm = 1; mm <= 8; mm <<= 1) sm += __shfl_xor(sm, mm, 64);
        mxr[r] = mx;
        if (fr == 0) { redm[wv][4 * g + r] = mx; reds[wv][4 * g + r] = sm; }
    }
    __syncthreads();

    float scl[4];
    #pragma unroll
    for (int r = 0; r < 4; ++r) {
        const int q = 4 * g + r;
        float mm = fmaxf(fmaxf(redm[0][q], redm[1][q]), fmaxf(redm[2][q], redm[3][q]));
        float ll = 0.f;
        #pragma unroll
        for (int w2 = 0; w2 < 4; ++w2) ll += reds[w2][q] * __expf(redm[w2][q] - mm);
        scl[r] = __expf(mxr[r] - mm) / ll;   // e * scl == exp(s-gm)*gl
    }
    #pragma unroll
    for (int kt = 0; kt < 16; ++kt) {
        #pragma unroll
        for (int r = 0; r < 4; ++r) {
            pb[4 * g + r][kbase + kt * 16 + fr] = __float2bfloat16(sfr[kt][r] * scl[r]);
        }
    }

    f32x4 o0 = {0.f, 0.f, 0.f, 0.f}, o1 = {0.f, 0.f, 0.f, 0.f};
    const __hip_bfloat16* vbase = vT + ((long long)bb * DIM + h * HD) * 1024;
    #pragma unroll
    for (int ksb = 0; ksb < 2; ++ksb) {
        bf16x8 pf[4], v0[4], v1[4];
        #pragma unroll
        for (int j = 0; j < 4; ++j) {
            const int key0 = kbase + (ksb * 4 + j) * 32 + g * 8;
            pf[j] = *(const bf16x8*)&pb[fr][key0];
            v0[j] = *(const bf16x8*)(vbase + (long long)fr * 1024 + key0);
            v1[j] = *(const bf16x8*)(vbase + (long long)(16 + fr) * 1024 + key0);
        }
        __builtin_amdgcn_sched_barrier(0);
        #pragma unroll
        for (int j = 0; j < 4; ++j) {
            o0 = __builtin_amdgcn_mfma_f32_16x16x32_bf16(pf[j], v0[j], o0, 0, 0, 0);
            o1 = __builtin_amdgcn_mfma_f32_16x16x32_bf16(pf[j], v1[j], o1, 0, 0, 0);
        }
    }

    __syncthreads();   // all waves done reading pb before redo overwrites it
    #pragma unroll
    for (int r = 0; r < 4; ++r) {
        redo[wv][4 * g + r][fr] = o0[r];
        redo[wv][4 * g + r][16 + fr] = o1[r];
    }
    __syncthreads();
    #pragma unroll
    for (int i = 0; i < 2; ++i) {
        const int idx = t + i * 256;
        const int q = idx >> 5, d = idx & 31;
        float v = redo[0][q][d] + redo[1][q][d] + redo[2][q][d] + redo[3][q][d];
        attout[((long long)(bb * NQ + q0 + q)) * DIM + h * HD + d] = __float2bfloat16(v);
    }
}

// ---------------- residual + LayerNorm, fused epilogues ----------------
extern "C" __global__ __launch_bounds__(256)
void ln_kernel(const float* __restrict__ X, long long sx,
               const float* __restrict__ R, long long sr,
               const float* __restrict__ g, const float* __restrict__ bta,
               float* __restrict__ O, long long so,
               __hip_bfloat16* __restrict__ Ob,
               const float* __restrict__ P,
               __hip_bfloat16* __restrict__ Qb,
               const int* __restrict__ gidx,
               float* __restrict__ OG) {
    __shared__ float red[4];
    const int row = blockIdx.x, bb = blockIdx.y, t = threadIdx.x;
    float x = X[(long long)bb * sx + (long long)row * DIM + t]
            + R[(long long)bb * sr + (long long)row * DIM + t];
    float v = x;
    #pragma unroll
    for (int m = 32; m >= 1; m >>= 1) v += __shfl_xor(v, m, 64);
    if ((t & 63) == 0) red[t >> 6] = v;
    __syncthreads();
    float mean = (red[0] + red[1] + red[2] + red[3]) * (1.f / 256.f);
    __syncthreads();
    float d = x - mean;
    v = d * d;
    #pragma unroll
    for (int m = 32; m >= 1; m >>= 1) v += __shfl_xor(v, m, 64);
    if ((t & 63) == 0) red[t >> 6] = v;
    __syncthreads();
    float var = (red[0] + red[1] + red[2] + red[3]) * (1.f / 256.f);
    float o = d * rsqrtf(var + 1e-5f) * g[t] + bta[t];
    const long long ofs = (long long)bb * so + (long long)row * DIM + t;
    if (gidx) {
        const int i = gidx[bb * NSEL + row];
        OG[((long long)(bb * HW_N + i)) * DIM + t] = o;
    } else {
        O[ofs] = o;
        if (Ob) Ob[ofs] = __float2bfloat16(o);
        if (Qb) Qb[ofs] = __float2bfloat16(o + P[ofs]);
    }
}

// ---------------- box attention, L2-local (one head-plane per block) ----------
extern "C" __global__ __launch_bounds__(256)
void boxattn_kernel(const float* __restrict__ qout, const float* __restrict__ selref,
                    const __hip_bfloat16* __restrict__ vp, const float* __restrict__ kidx,
                    __hip_bfloat16* __restrict__ boxout) {
    __shared__ float aw_s[400];
    __shared__ float ob_s[64];
    __shared__ float ref_s[112];
    __shared__ float ki_s[50];
    __shared__ float dg_s[800];
    __shared__ float box_s[16][6];
    __shared__ float mx_s[16];
    __shared__ float inv_s[16];
    __shared__ float wq_s[400];
    __shared__ int   i4_s[1600];
    __shared__ float w4_s[1600];
    const int t = threadIdx.x;
    const int combo = blockIdx.x;            // b*8 + h
    const int bb = combo >> 3, h = combo & 7;
    const int s0 = blockIdx.y * 16;
    const long long base = (long long)bb * NSEL + s0;

    #pragma unroll
    for (int e = t; e < 400; e += 256) {
        const int s = e / 25, p = e - s * 25;
        aw_s[e] = qout[(base + s) * NQOUT + h * 25 + p];
    }
    if (t < 64)  ob_s[t] = qout[(base + (t >> 2)) * NQOUT + 200 + h * 4 + (t & 3)];
    if (t < 112) ref_s[t] = selref[base * 7 + t];
    if (t < 50)  ki_s[t] = kidx[t];
    #pragma unroll
    for (int e = t; e < 800; e += 256) {
        const int s = e / 50, r = e - s * 50;
        dg_s[e] = qout[(base + s) * NQOUT + 232 + h * 50 + r];
    }
    __syncthreads();

    if (t < 16) {
        float mx = -1e30f;
        #pragma unroll
        for (int p = 0; p < NP_; ++p) mx = fmaxf(mx, aw_s[t * NP_ + p]);
        mx_s[t] = mx;
        const float r0 = ref_s[t * 7 + 0], r1 = ref_s[t * 7 + 1];
        const float r3 = ref_s[t * 7 + 3], r4 = ref_s[t * 7 + 4], r6 = ref_s[t * 7 + 6];
        box_s[t][0] = r0 + ob_s[t * 4 + 0] * 0.125f * r3;
        box_s[t][1] = r1 + ob_s[t * 4 + 1] * 0.125f * r4;
        box_s[t][2] = fmaxf(r3 + ob_s[t * 4 + 2] * 0.125f * r3, 0.f);
        box_s[t][3] = fmaxf(r4 + ob_s[t * 4 + 3] * 0.125f * r4, 0.f);
        box_s[t][4] = cosf(r6);
        box_s[t][5] = sinf(r6);
    }
    __syncthreads();

    #pragma unroll
    for (int e = t; e < 400; e += 256) {
        const int s = e / 25, p = e - s * 25;
        const float w = __expf(aw_s[e] - mx_s[s]);
        wq_s[e] = w;
        const float cx = box_s[s][0], cy = box_s[s][1];
        const float sw = box_s[s][2], sh = box_s[s][3];
        const float ca = box_s[s][4], sa = box_s[s][5];
        const float fx = ki_s[p * 2 + 0] * sw;
        const float fy = ki_s[p * 2 + 1] * sh;
        const float gx = cx + ca * fx - sa * fy + dg_s[s * 50 + 2 * p + 0] * (1.f / 188.f);
        const float gy = cy + sa * fx + ca * fy + dg_s[s * 50 + 2 * p + 1] * (1.f / 188.f);
        const float x = gx * 128.f - 0.5f;
        const float y = gy * 128.f - 0.5f;
        const float x0f = floorf(x), y0f = floorf(y);
        const float lx = x - x0f, ly = y - y0f;
        const int x0 = (int)x0f, y0 = (int)y0f;
        #pragma unroll
        for (int c = 0; c < 4; ++c) {
            const int xi = x0 + (c & 1);
            const int yi = y0 + (c >> 1);
            const float wgt = ((c & 1) ? lx : 1.f - lx) * ((c >> 1) ? ly : 1.f - ly);
            const bool valid = (xi >= 0) & (xi < 128) & (yi >= 0) & (yi < 128);
            const int cxi = min(max(xi, 0), 127);
            const int cyi = min(max(yi, 0), 127);
            i4_s[e * 4 + c] = cyi * 128 + cxi;
            w4_s[e * 4 + c] = w * (valid ? wgt : 0.f);
        }
    }
    __syncthreads();

    if (t < 16) {
        float sm = 0.f;
        #pragma unroll
        for (int p = 0; p < NP_; ++p) sm += wq_s[t * NP_ + p];
        inv_s[t] = 1.f / sm;
    }

    {
        const int lane = t & 63;
        const int s_loc = t >> 4;
        const int j2 = (lane >> 2) & 3;
        const int q2 = lane & 3;
        const __hip_bfloat16* vb = vp + ((long long)(bb * 8 + h) * 16384) * 32 + q2 * 8;
        const int ebase = s_loc * 100;
        float a[8] = {0.f, 0.f, 0.f, 0.f, 0.f, 0.f, 0.f, 0.f};
        #pragma unroll
        for (int u = 0; u < 25; ++u) {
            const int ii = ebase + j2 + 4 * u;
            bf16x8 v = *(const bf16x8*)(vb + (long long)i4_s[ii] * 32);
            const float w = w4_s[ii];
            #pragma unroll
            for (int k = 0; k < 8; ++k) a[k] += w * (float)v[k];
        }
        #pragma unroll
        for (int k = 0; k < 8; ++k) a[k] += __shfl_xor(a[k], 4, 64);
        #pragma unroll
        for (int k = 0; k < 8; ++k) a[k] += __shfl_xor(a[k], 8, 64);
        __syncthreads();
        if (j2 == 0) {
            const float inv = inv_s[s_loc];
            __hip_bfloat16* op = boxout + (base + s_loc) * DIM + h * HD + q2 * 8;
            bf16x8 o;
            #pragma unroll
            for (int k = 0; k < 8; ++k) o[k] = __float2bfloat16(a[k] * inv);
            *(bf16x8*)op = o;
        }
    }
}

extern "C" void kernel_launch(void* const* d_in, const int* in_sizes, int n_in,
                              void* d_out, int out_size, void* d_ws, size_t ws_size,
                              hipStream_t stream) {
    const float* src          = (const float*)d_in[0];
    const float* pos          = (const float*)d_in[1];
    const float* refw         = (const float*)d_in[4];
    const float* score        = (const float*)d_in[5];
    const float* in_proj_w    = (const float*)d_in[6];
    const float* in_proj_b    = (const float*)d_in[7];
    const float* mha_out_w    = (const float*)d_in[8];
    const float* mha_out_b    = (const float*)d_in[9];
    const float* value_proj_w = (const float*)d_in[10];
    const float* value_proj_b = (const float*)d_in[11];
    const float* lin_attn_w   = (const float*)d_in[12];
    const float* lin_attn_b   = (const float*)d_in[13];
    const float* lin_box_w    = (const float*)d_in[14];
    const float* lin_box_b    = (const float*)d_in[15];
    const float* samp_off_w   = (const float*)d_in[16];
    const float* samp_off_b   = (const float*)d_in[17];
    const float* ca_out_w     = (const float*)d_in[18];
    const float* ca_out_b     = (const float*)d_in[19];
    const float* lin1_w       = (const float*)d_in[20];
    const float* lin1_b       = (const float*)d_in[21];
    const float* lin2_w       = (const float*)d_in[22];
    const float* lin2_b       = (const float*)d_in[23];
    const float* qn_g         = (const float*)d_in[24];
    const float* qn_b         = (const float*)d_in[25];
    const float* n1_g         = (const float*)d_in[26];
    const float* n1_b         = (const float*)d_in[27];
    const float* n2_g         = (const float*)d_in[28];
    const float* n2_b         = (const float*)d_in[29];
    const float* kidx         = (const float*)d_in[30];

    float* w = (float*)d_ws;
    int* idxp = (int*)d_ws;
    float* selref = w + OFF_SELREF;
    float* selsrc = w + OFF_SELSRC;
    float* selpos = w + OFF_SELPOS;
    __hip_bfloat16* boxoutb = (__hip_bfloat16*)(w + OFF_SELPOS);  // reuse after selpos dead
    __hip_bfloat16* queryb  = (__hip_bfloat16*)(w + OFF_QUERY);   // bf16 query
    float* src2   = w + OFF_QUERY;    // reuse after queryb dead
    __hip_bfloat16* vproj  = (__hip_bfloat16*)(w + OFF_BIG);   // head-planar bf16
    __hip_bfloat16* ffntb  = (__hip_bfloat16*)(w + OFF_BIG);   // reuse after vproj dead
    __hip_bfloat16* wbf    = (__hip_bfloat16*)(w + OFF_WBF);   // bf16 weight pool
    float* qbias  = w + OFF_QBIAS;                              // packed 632-float bias
    __hip_bfloat16* qkbin   = (__hip_bfloat16*)(w + OFF_F);            // qk bf16 (A of qkv gemm)
    __hip_bfloat16* selsrcb = (__hip_bfloat16*)(w + OFF_F + 262144);   // selsrc bf16 rows 0..NQ
    __hip_bfloat16* qkb = (__hip_bfloat16*)(w + OFF_F + 524288);       // qkv gemm out
    __hip_bfloat16* vT  = (__hip_bfloat16*)(w + OFF_F + 1572864);
    __hip_bfloat16* attoutb = (__hip_bfloat16*)(w + OFF_F + 2097152);  // attn out bf16
    float* q2     = w + OFF_F + 2621440;
    float* qout   = w + OFF_F;              // fused query-GEMM out [2*4096][632] (reuse after MHA dead)
    float* ff     = w + OFF_F;              // reuse after box-attn dead
    __hip_bfloat16* selsrcb2 = (__hip_bfloat16*)(w + OFF_F + 1048576); // n1-LN bf16 out (A of lin1)
    __hip_bfloat16* srcb = (__hip_bfloat16*)(w + OFF_SRCB);    // bf16 copy of src
    unsigned int* hist2 = (unsigned int*)(w + OFF_F);          // topk scratch
    unsigned int* ctrl2 = hist2 + 16384;
    unsigned long long* list1 = (unsigned long long*)(hist2 + 16448);
    unsigned long long* list2 = list1 + 2 * 2048;
    float* out    = (float*)d_out;

    const bool big_ws = (ws_size >= (size_t)WS_NEED_B2);

    // bf16 weight pool offsets (W_LATTN..W_SOFF are CONTIGUOUS -> fused [632][256])
    const long long W_INPROJ = 0, W_MHAOUT = 196608, W_VALUE = 262144,
                    W_LATTN = 327680, W_LBOX = 378880, W_SOFF = 387072,
                    W_CAOUT = 489472, W_LIN1 = 555008, W_LIN2 = 817152;

    hipMemcpyAsync(d_out, src, (size_t)2 * HW_N * DIM * sizeof(float),
                   hipMemcpyDeviceToDevice, stream);

    wcvt_kernel<<<4217, 256, 0, stream>>>(in_proj_w, mha_out_w, value_proj_w,
                                          lin_attn_w, lin_box_w, samp_off_w,
                                          ca_out_w, lin1_w, lin2_w, wbf,
                                          lin_attn_b, lin_box_b, samp_off_b, qbias);
    if (big_ws)
        scvt_kernel<<<4096, 256, 0, stream>>>(src, srcb);

    hipMemsetAsync(hist2, 0, 16448 * sizeof(unsigned int), stream);
    topk_hist_kernel<<<dim3(32, 2), 512, 0, stream>>>(score, hist2);
    topk_scan_kernel<<<2, 1024, 0, stream>>>(hist2, ctrl2);
    topk_collect_kernel<<<dim3(16, 2), 1024, 0, stream>>>(score, ctrl2, list1, list2);
    topk_classify_kernel<<<dim3(16, 2), 1024, 0, stream>>>(score, ctrl2, list1, list2, idxp);

    gather_kernel<<<dim3(NSEL, 2), 256, 0, stream>>>(src, pos, refw, idxp,
                                                     selsrc, selpos, selref,
                                                     qkbin, selsrcb, queryb);
    // fused in_proj: qkv (N=512) + vT (N=256) in one 384-block launch
    gemm_dual_kernel<<<dim3(12, 16, 2), 256, 0, stream>>>(qkbin, selsrcb, wbf + W_INPROJ,
                                                          in_proj_b, qkb, vT);
    attn_kernel<<<dim3(64, 8, 2), 256, 0, stream>>>(qkb, vT, attoutb);
    gemm_kernel<<<dim3(4, 16, 2), 256, 0, stream>>>(attoutb, 262144LL, wbf + W_MHAOUT, mha_out_b,
                                                    q2, 262144LL, NQ, 256, 256, 0, 0, 1);
    // qn-LN fused with addq: queryb rows [0,NQ) = bf16(ln_out + selpos)
    ln_kernel<<<dim3(NQ, 2), 256, 0, stream>>>(selsrc, 1048576LL, q2, 262144LL,
                                               qn_g, qn_b, selsrc, 1048576LL,
                                               nullptr, selpos, queryb, nullptr, nullptr);
    // vproj (64^2-tile): bf16 A when workspace allows (pure 16B staging copies,
    // half the A re-read traffic); numerically identical to fp32-A staging.
    if (big_ws) {
        gemm_kernel<<<dim3(4, 256, 2), 256, 0, stream>>>(srcb, 4194304LL, wbf + W_VALUE, value_proj_b,
                                                         (float*)vproj, 4194304LL, HW_N, 256, 256, 0, 3, 1);
    } else {
        gemm_kernel<<<dim3(4, 256, 2), 256, 0, stream>>>(src, 4194304LL, wbf + W_VALUE, value_proj_b,
                                                         (float*)vproj, 4194304LL, HW_N, 256, 256, 0, 3, 0);
    }
    // fused query GEMM: [aw | ob | dgrid] = query @ [W_LATTN;W_LBOX;W_SOFF]^T + qbias
    gemm_kernel<<<dim3(10, 64, 2), 256, 0, stream>>>(queryb, 1048576LL, wbf + W_LATTN, qbias,
                                                     qout, (long long)NSEL * NQOUT,
                                                     NSEL, NQOUT, 256, 0, 0, 1);
    boxattn_kernel<<<dim3(16, 256), 256, 0, stream>>>(qout, selref, vproj, kidx, boxoutb);
    gemm_kernel<<<dim3(4, 64, 2), 256, 0, stream>>>(boxoutb, 1048576LL, wbf + W_CAOUT, ca_out_b,
                                                    src2, 1048576LL, NSEL, 256, 256, 0, 0, 1);
    ln_kernel<<<dim3(NSEL, 2), 256, 0, stream>>>(selsrc, 1048576LL, src2, 1048576LL,
                                                 n1_g, n1_b, selsrc, 1048576LL,
                                                 selsrcb2, nullptr, nullptr, nullptr, nullptr);
    gemm_kernel<<<dim3(16, 64, 2), 256, 0, stream>>>(selsrcb2, 1048576LL, wbf + W_LIN1, lin1_b,
                                                     (float*)ffntb, 4194304LL, NSEL, DFF_, 256, 1, 1, 1);
    gemm_kernel<<<dim3(4, 64, 2), 256, 0, stream>>>(ffntb, 4194304LL, wbf + W_LIN2, lin2_b,
                                                    ff, 1048576LL, NSEL, 256, DFF_, 0, 0, 1);
    // n2-LN fused with scatter: write directly to out[idx]
    ln_kernel<<<dim3(NSEL, 2), 256, 0, stream>>>(selsrc, 1048576LL, ff, 1048576LL,
                                                 n2_g, n2_b, nullptr, 1048576LL,
                                                 nullptr, nullptr, nullptr, idxp, out);
}